// Round 12
// baseline (178.815 us; speedup 1.0000x reference)
//
#include <hip/hip_runtime.h>

typedef _Float16 v8h __attribute__((ext_vector_type(8)));
typedef _Float16 v4h __attribute__((ext_vector_type(4)));
typedef _Float16 v2h __attribute__((ext_vector_type(2)));
typedef float v4f __attribute__((ext_vector_type(4)));

#define NB 64
#define CI 96
#define CE 576
#define CO 96
#define HW 784
#define SEC 144

#if defined(__has_builtin)
#if __has_builtin(__builtin_amdgcn_fdot2)
#define HAVE_FDOT2 1
#endif
#endif

__device__ __forceinline__ float fdot2(v2h a, v2h b, float c) {
#ifdef HAVE_FDOT2
  return __builtin_amdgcn_fdot2(a, b, c, false);
#else
  return (float)a[0] * (float)b[0] + ((float)a[1] * (float)b[1] + c);
#endif
}

// ---------------- K0x: pack x into MFMA-fragment layout + x_h + weight cvt ----
// Split by ci-32-group s: grid (7 hw-tiles, 3 s, NB) = 1344 blocks (was 448 at
// 1.75/CU -> 2:1 CU imbalance). Each block stages 32 channels x 112 px and
// writes only its s-slice of x_f / x_h. n==0,s==0 blocks also convert weights.
__global__ __launch_bounds__(256) void k0x_pack(const float* __restrict__ x,
                                                const float* __restrict__ w_exp,
                                                const float* __restrict__ w_proj,
                                                _Float16* __restrict__ x_f,
                                                _Float16* __restrict__ x_h,
                                                _Float16* __restrict__ w_exp_h,
                                                _Float16* __restrict__ w_proj_h) {
  __shared__ _Float16 xl[112][40];   // [hw_local][ci32], pad 32->40 (80B rows, 16B-aligned frags)
  const int tid = threadIdx.x;
  const int s = blockIdx.y;
  const int n = blockIdx.z;
  const int hw0 = blockIdx.x * 112;

  if (n == 0 && s == 0) {  // weight conversion folded in (7 blocks)
    for (int i = blockIdx.x * 256 + tid; i < CE * CI; i += 7 * 256) {
      w_exp_h[i]  = (_Float16)w_exp[i];
      w_proj_h[i] = (_Float16)w_proj[i];
    }
  }

  for (int idx = tid; idx < 32 * 28; idx += 256) {
    int c_l = idx / 28, seg = idx % 28;
    int c = s * 32 + c_l;
    const float4 v = *(const float4*)&x[(n * CI + c) * HW + hw0 + seg * 4];
    v4h xh;
    xh[0] = (_Float16)(v.x - 128.0f);
    xh[1] = (_Float16)(v.y - 128.0f);
    xh[2] = (_Float16)(v.z - 128.0f);
    xh[3] = (_Float16)(v.w - 128.0f);
    int row = seg * 4;
    xl[row + 0][c_l] = xh[0];
    xl[row + 1][c_l] = xh[1];
    xl[row + 2][c_l] = xh[2];
    xl[row + 3][c_l] = xh[3];
    *(v4h*)&x_h[(n * CI + c) * HW + hw0 + seg * 4] = xh;   // k4 residual input
  }
  __syncthreads();

  for (int idx = tid; idx < 448; idx += 256) {   // 7 t_l * 64 lanes
    int t_l = idx / 64, ln = idx % 64;
    int hw_l = t_l * 16 + (ln & 15), ci = (ln >> 4) * 8;
    v8h o = *(const v8h*)&xl[hw_l][ci];          // aligned b128
    size_t t = (size_t)(blockIdx.x * 7 + t_l);
    *(v8h*)&x_f[(((size_t)n * 49 + t) * 3 + s) * 512 + ln * 8] = o;
  }
}

// ---------------- K12: FUSED expand 1x1 (MFMA) + depthwise 5x5 ---------------
// block = (c-group of 16, image-half of 14 rows, n), 448 thr (7 waves):
//  - phase 1: exactly 4 t-tiles per wave (28/7) -> no barrier imbalance
//  - phase 2: c = tid/28, l = tid%28 -> all 448 lanes active (was 28/32)
//  - pool sums via LDS reduction by 16 spare threads DURING phase-3 writeout
// LDS 39.8 KB -> 4 blocks/CU = 28 waves. Round-9 tap math (r10 variants lost).
__global__ __launch_bounds__(448, 7) void k12_fused(const _Float16* __restrict__ x_f,
                                                    const _Float16* __restrict__ w_exp_h,
                                                    const float* __restrict__ b_exp,
                                                    const float* __restrict__ w_dw,
                                                    const float* __restrict__ b_dw,
                                                    _Float16* __restrict__ d_t,
                                                    float* __restrict__ d_sums2) {
  __shared__ _Float16 e_lds[16][18][42];   // 24192 B; row stride 21 dw (odd)
  __shared__ _Float16 d_tile[16][392];     // 12544 B
  __shared__ _Float16 w_pairs[16][5][8];   // 1280 B: [c][dy][w0..w3, w1..w4]
  __shared__ float red[448];               // 1792 B: per-thread pool partials
  const int tid = threadIdx.x;
  const int n = blockIdx.z;
  const int h = blockIdx.y;                // image half: rows 14h..14h+13
  const int c0 = blockIdx.x * 16;

  // zero conv image (covers halo + tails)
  {
    unsigned long long* z = (unsigned long long*)&e_lds[0][0][0];
    for (int idx = tid; idx < 16 * 18 * 42 * 2 / 8; idx += 448) z[idx] = 0ull;
  }
  for (int idx = tid; idx < 640; idx += 448) {
    int c = idx / 40, r = idx % 40, dy = r / 8, k = r % 8;
    int tap = (k < 4) ? k : (k - 3);
    w_pairs[c][dy][k] = (_Float16)w_dw[(c0 + c) * 25 + dy * 5 + tap];
  }
  __syncthreads();

  const int wv = tid >> 6, lane = tid & 63;
  const int l15 = lane & 15, q = lane >> 4;

  // ---- phase 1: expand GEMM; lane owns pixels t*16+q*4..+3 of channel c0+l15 --
  {
    const _Float16* wrow = &w_exp_h[(c0 + l15) * CI + q * 8];
    v8h b0 = *(const v8h*)(wrow);          // B-frag: n=channel, k=ci
    v8h b1 = *(const v8h*)(wrow + 32);
    v8h b2 = *(const v8h*)(wrow + 64);
    const float bia = b_exp[c0 + l15];

    const int ir0 = 14 * h - 2;            // input row stored at LDS row 0
    const _Float16* xb = x_f + (size_t)n * (49 * 3 * 512) + lane * 8;
#pragma unroll
    for (int i = 0; i < 4; ++i) {          // 4 tiles per wave, 7 waves = 28
      int t_l = wv + 7 * i;
      int t = 21 * h + t_l;
      const _Float16* xt = xb + (size_t)t * (3 * 512);
      v8h a0 = *(const v8h*)(xt);          // A-frag: m=pixel, k=ci
      v8h a1 = *(const v8h*)(xt + 512);
      v8h a2 = *(const v8h*)(xt + 1024);
      v4f acc = (v4f){0.f, 0.f, 0.f, 0.f};
      acc = __builtin_amdgcn_mfma_f32_16x16x32_f16(a0, b0, acc, 0, 0, 0);
      acc = __builtin_amdgcn_mfma_f32_16x16x32_f16(a1, b1, acc, 0, 0, 0);
      acc = __builtin_amdgcn_mfma_f32_16x16x32_f16(a2, b2, acc, 0, 0, 0);
      int p = t * 16 + q * 4;              // 4 consecutive pixels, same row
      int y = p / 28, xx = p - y * 28;     // xx % 4 == 0
      int r_l = y - ir0;
      v4h ev;
#pragma unroll
      for (int r = 0; r < 4; ++r) {
        float deq = (acc[r] + bia) * 5.0e-4f;               // S_IN * W_SCALE
        float cl  = fminf(fmaxf(deq + 3.0f, 0.0f), 6.0f);
        float evf = fminf(fmaxf(deq * cl * (25.0f / 6.0f), -128.0f), 127.0f); // e-128
        ev[r] = (_Float16)evf;
      }
      *(v4h*)&e_lds[l15][r_l][8 + xx] = ev;   // 8B-aligned b64
    }
  }
  __syncthreads();

  // ---- phase 2: depthwise 5x5 (round-9 form); c = tid/28, all lanes active ----
  const int c = tid / 28, l = tid % 28;
  v2h W01[5], W23[5], W12[5], W34[5];
  float W0s[5], W4s[5];
#pragma unroll
  for (int dy = 0; dy < 5; ++dy) {
    W01[dy] = *(const v2h*)&w_pairs[c][dy][0];
    W23[dy] = *(const v2h*)&w_pairs[c][dy][2];
    W12[dy] = *(const v2h*)&w_pairs[c][dy][4];
    W34[dy] = *(const v2h*)&w_pairs[c][dy][6];
    W0s[dy] = (float)W01[dy][0];
    W4s[dy] = (float)W34[dy][1];
  }
  const float bc = b_dw[c0 + c];

  float csum = 0.0f;
  {
    const int ry = l >> 1;       // local output row 0..13
    const int bx = (l & 1) * 14; // x-half base
    // P_i = pixels (x0-2+2i, x0-1+2i); pixel p at half p+8
    v2h P0[5], P1[5], P2[5], P3[5];
#pragma unroll
    for (int dy = 0; dy < 5; ++dy) {
      const _Float16* row = &e_lds[c][ry + dy][bx];
      P0[dy] = *(const v2h*)(row + 6);
      P1[dy] = *(const v2h*)(row + 8);
      P2[dy] = *(const v2h*)(row + 10);
      P3[dy] = *(const v2h*)(row + 12);
    }
#pragma unroll
    for (int xi = 0; xi < 3; ++xi) {      // x0 = bx, bx+4, bx+8
      const int x0 = bx + xi * 4;
      float o0 = bc, o1 = bc, o2 = bc, o3 = bc;
#pragma unroll
      for (int dy = 0; dy < 5; ++dy) {
        o0 = fdot2(P0[dy], W01[dy], o0);
        o0 = fdot2(P1[dy], W23[dy], o0);
        o0 += (float)P2[dy][0] * W4s[dy];
        o1 += (float)P0[dy][1] * W0s[dy];
        o1 = fdot2(P1[dy], W12[dy], o1);
        o1 = fdot2(P2[dy], W34[dy], o1);
        o2 = fdot2(P1[dy], W01[dy], o2);
        o2 = fdot2(P2[dy], W23[dy], o2);
        o2 += (float)P3[dy][0] * W4s[dy];
        o3 += (float)P1[dy][1] * W0s[dy];
        o3 = fdot2(P2[dy], W12[dy], o3);
        o3 = fdot2(P3[dy], W34[dy], o3);
      }
      float oo[4] = {o0, o1, o2, o3};
      v2h dva, dvb;
#pragma unroll
      for (int i = 0; i < 4; ++i) {
        float deq = oo[i] * 4.0e-4f;            // S1 * W_SCALE
        float cl  = fminf(fmaxf(deq + 3.0f, 0.0f), 6.0f);
        float dvv = fminf(fmaxf(deq * cl * (25.0f / 6.0f), -128.0f), 127.0f); // d-128
        if (i < 2) dva[i] = (_Float16)dvv; else dvb[i - 2] = (_Float16)dvv;
        csum += dvv;
      }
      *(v2h*)&d_tile[c][ry * 28 + x0]     = dva;
      *(v2h*)&d_tile[c][ry * 28 + x0 + 2] = dvb;
#pragma unroll
      for (int dy = 0; dy < 5; ++dy) {        // slide; reads stay in-row (zero tail)
        const _Float16* row = &e_lds[c][ry + dy][bx];
        P0[dy] = P2[dy];
        P1[dy] = P3[dy];
        P2[dy] = *(const v2h*)(row + x0 - bx + 14);
        P3[dy] = *(const v2h*)(row + x0 - bx + 16);
      }
    }
    {  // tail: x0 = bx+12, outputs o0,o1 only
      float o0 = bc, o1 = bc;
#pragma unroll
      for (int dy = 0; dy < 5; ++dy) {
        o0 = fdot2(P0[dy], W01[dy], o0);
        o0 = fdot2(P1[dy], W23[dy], o0);
        o0 += (float)P2[dy][0] * W4s[dy];
        o1 += (float)P0[dy][1] * W0s[dy];
        o1 = fdot2(P1[dy], W12[dy], o1);
        o1 = fdot2(P2[dy], W34[dy], o1);
      }
      v2h dv;
      float oo[2] = {o0, o1};
#pragma unroll
      for (int i = 0; i < 2; ++i) {
        float deq = oo[i] * 4.0e-4f;
        float cl  = fminf(fmaxf(deq + 3.0f, 0.0f), 6.0f);
        float dvv = fminf(fmaxf(deq * cl * (25.0f / 6.0f), -128.0f), 127.0f);
        dv[i] = (_Float16)dvv;
        csum += dvv;
      }
      *(v2h*)&d_tile[c][ry * 28 + bx + 12] = dv;
    }
  }
  red[tid] = csum;
  __syncthreads();

  // ---- phase 3: k-packed writeout (tid<392) + pool reduction (tid 392..407) ----
  if (tid < 392) {
    int hw_l = tid;
    const size_t obase = ((size_t)n * 72 + (c0 >> 3)) * 784 + 392 * h;
    v8h o0, o1;
#pragma unroll
    for (int j = 0; j < 8; ++j) { o0[j] = d_tile[j][hw_l]; o1[j] = d_tile[8 + j][hw_l]; }
    *(v8h*)&d_t[(obase + hw_l) * 8] = o0;
    *(v8h*)&d_t[(obase + 784 + hw_l) * 8] = o1;
  } else if (tid < 408) {
    int cc = tid - 392;                    // channel 0..15
    float s = 0.f;
#pragma unroll
    for (int k = 0; k < 28; ++k) s += red[cc * 28 + k];
    d_sums2[((size_t)h * NB + n) * CE + c0 + cc] = s;
  }
}

// ---------------- K3a: SE fc1 — one wave per (n, o); sums 2 pool partials -----
__global__ __launch_bounds__(256) void k3a_fc1(const float* __restrict__ d_sums2,
                                               const float* __restrict__ w_se1,
                                               const float* __restrict__ b_se1,
                                               float* __restrict__ g1) {
  const int tid = threadIdx.x;
  const int wv = tid >> 6, lane = tid & 63;
  const int n = blockIdx.y;
  const int o = blockIdx.x * 4 + wv;       // 144 outputs
  const float* wrow = &w_se1[o * CE];
  const float* s0 = &d_sums2[(size_t)n * CE];
  const float* s1 = &d_sums2[((size_t)NB + n) * CE];
  float p = 0.f;
#pragma unroll
  for (int s = 0; s < 9; ++s) {
    int cc = lane + s * 64;
    p += wrow[cc] * (s0[cc] + s1[cc]);
  }
#pragma unroll
  for (int m = 32; m >= 1; m >>= 1) p += __shfl_xor(p, m);
  if (lane == 0) {
    float deq = (p * (1.0f / 784.0f) + b_se1[o]) * 4.0e-4f;  // S2 * W_SCALE
    g1[n * SEC + o] = fminf(fmaxf(deq * 33.3333333f + 128.0f, 0.0f), 255.0f) - 128.0f;
  }
}

// ---------------- K3b: SE fc2 + hardsigmoid -> f16 gate table -----------------
__global__ __launch_bounds__(256) void k3b_fc2(const float* __restrict__ g1,
                                               const float* __restrict__ w_se2,
                                               const float* __restrict__ b_se2,
                                               _Float16* __restrict__ g2h) {
  const int tid = threadIdx.x;
  const int wv = tid >> 6, lane = tid & 63;
  const int n = blockIdx.y;
  const int o = blockIdx.x * 4 + wv;       // 576 outputs
  const float* wrow = &w_se2[o * SEC];
  const float* grow = &g1[n * SEC];
  float p = wrow[lane] * grow[lane] + wrow[lane + 64] * grow[lane + 64];
  if (lane < 16) p += wrow[lane + 128] * grow[lane + 128];
#pragma unroll
  for (int m = 32; m >= 1; m >>= 1) p += __shfl_xor(p, m);
  if (lane == 0) {
    float deq = (p + b_se2[o]) * 3.0e-4f;  // S_SE1 * W_SCALE
    g2h[n * CE + o] =
        (_Float16)(fminf(fmaxf(deq + 3.0f, 0.0f), 6.0f) * (1.0f / 6.0f)); // hardsigmoid
  }
}

// ---------------- K4: gated project 1x1 + residual add -> out fp32 -----------
// No LDS/barriers, 7 independent accumulators per wave for load ILP.
// Gate folded into the A fragment. M-split co-groups of 48 -> 896 blocks.
// Residual read from x_h (f16, half the traffic of fp32 x).
__global__ __launch_bounds__(192) void k4_proj(const _Float16* __restrict__ d_t,
                                               const _Float16* __restrict__ g2h,
                                               const _Float16* __restrict__ w_proj_h,
                                               const float* __restrict__ b_proj,
                                               const _Float16* __restrict__ x_h,
                                               float* __restrict__ out) {
  const int tid = threadIdx.x;
  const int n = blockIdx.z;
  const int co0 = blockIdx.y * 48;
  const int hw0 = blockIdx.x * 112;
  const int wv = tid >> 6, lane = tid & 63;
  const int l15 = lane & 15, q = lane >> 4;

  v4f acc[7];
#pragma unroll
  for (int t = 0; t < 7; ++t) acc[t] = (v4f){0.f, 0.f, 0.f, 0.f};

  const _Float16* dbase = d_t + (((size_t)n * 72 + q) * 784 + hw0 + l15) * 8;
  const _Float16* abase = &w_proj_h[(co0 + wv * 16 + l15) * CE + q * 8];
  const _Float16* gbase = &g2h[(size_t)n * CE + q * 8];

  for (int ks = 0; ks < 18; ++ks) {
    v8h a = *(const v8h*)(abase + ks * 32);
    v8h g = *(const v8h*)(gbase + ks * 32);
    v8h ag = a * g;   // 4x v_pk_mul_f16, shared across the 7 MFMAs
    const _Float16* dk = dbase + (size_t)ks * (4 * 784 * 8);
#pragma unroll
    for (int t = 0; t < 7; ++t) {
      v8h b = *(const v8h*)(dk + t * (16 * 8));
      acc[t] = __builtin_amdgcn_mfma_f32_16x16x32_f16(ag, b, acc[t], 0, 0, 0);
    }
  }

  float bia[4];
#pragma unroll
  for (int r = 0; r < 4; ++r) bia[r] = b_proj[co0 + wv * 16 + q * 4 + r];

#pragma unroll
  for (int t = 0; t < 7; ++t) {
#pragma unroll
    for (int r = 0; r < 4; ++r) {
      int co = co0 + wv * 16 + q * 4 + r;
      int hw = hw0 + t * 16 + l15;
      float p = fminf(fmaxf((acc[t][r] + bia[r]) * 4.0e-4f * 20.0f + 128.0f, 0.0f), 255.0f);
      float xv = (float)x_h[(n * CO + co) * HW + hw];   // x - 128, f16-exact
      float o = xv * 0.8333333333f + (p - 128.0f) * 0.8333333333f + 128.0f;
      out[(n * CO + co) * HW + hw] = fminf(fmaxf(o, 0.0f), 255.0f);
    }
  }
}

extern "C" void kernel_launch(void* const* d_in, const int* in_sizes, int n_in,
                              void* d_out, int out_size, void* d_ws, size_t ws_size,
                              hipStream_t stream) {
  const float* x      = (const float*)d_in[0];
  const float* w_exp  = (const float*)d_in[1];
  const float* b_exp  = (const float*)d_in[2];
  const float* w_dw   = (const float*)d_in[3];
  const float* b_dw   = (const float*)d_in[4];
  const float* w_se1  = (const float*)d_in[5];
  const float* b_se1  = (const float*)d_in[6];
  const float* w_se2  = (const float*)d_in[7];
  const float* b_se2  = (const float*)d_in[8];
  const float* w_proj = (const float*)d_in[9];
  const float* b_proj = (const float*)d_in[10];
  float* out = (float*)d_out;

  char* ws = (char*)d_ws;
  const size_t SZ_W  = (size_t)CE * CI * 2;            // 110592 B
  const size_t SZ_XF = (size_t)NB * 49 * 3 * 512 * 2;  // 9633792 B
  const size_t SZ_XH = (size_t)NB * CI * HW * 2;       // 9633792 B
  const size_t SZ_D  = (size_t)NB * CE * HW * 2;       // 57802752 B
  const size_t SZ_S2 = (size_t)2 * NB * CE * 4;        // 294912 B
  const size_t SZ_S  = (size_t)NB * CE * 4;            // 147456 B
  _Float16* w_exp_h  = (_Float16*)(ws);
  _Float16* w_proj_h = (_Float16*)(ws + SZ_W);
  _Float16* x_f      = (_Float16*)(ws + 2 * SZ_W);
  _Float16* x_h      = (_Float16*)(ws + 2 * SZ_W + SZ_XF);
  _Float16* d_t      = (_Float16*)(ws + 2 * SZ_W + SZ_XF + SZ_XH);  // [n][72][784][8]
  float*    d_sums2  = (float*)   (ws + 2 * SZ_W + SZ_XF + SZ_XH + SZ_D);
  float*    g1       = (float*)   (ws + 2 * SZ_W + SZ_XF + SZ_XH + SZ_D + SZ_S2);
  _Float16* g2h      = (_Float16*)(ws + 2 * SZ_W + SZ_XF + SZ_XH + SZ_D + SZ_S2 + SZ_S);
  // total ws use: ~78 MB

  k0x_pack<<<dim3(7, 3, NB), 256, 0, stream>>>(x, w_exp, w_proj, x_f, x_h, w_exp_h, w_proj_h);
  k12_fused<<<dim3(36, 2, NB), 448, 0, stream>>>(x_f, w_exp_h, b_exp, w_dw, b_dw, d_t, d_sums2);
  k3a_fc1<<<dim3(36, NB), 256, 0, stream>>>(d_sums2, w_se1, b_se1, g1);
  k3b_fc2<<<dim3(144, NB), 256, 0, stream>>>(g1, w_se2, b_se2, g2h);
  k4_proj<<<dim3(7, 2, NB), 192, 0, stream>>>(d_t, g2h, w_proj_h, b_proj, x_h, out);
}

// Round 13
// 175.654 us; speedup vs baseline: 1.0180x; 1.0180x over previous
//
#include <hip/hip_runtime.h>

typedef _Float16 v8h __attribute__((ext_vector_type(8)));
typedef _Float16 v4h __attribute__((ext_vector_type(4)));
typedef _Float16 v2h __attribute__((ext_vector_type(2)));
typedef float v4f __attribute__((ext_vector_type(4)));

#define NB 64
#define CI 96
#define CE 576
#define CO 96
#define HW 784
#define SEC 144

#if defined(__has_builtin)
#if __has_builtin(__builtin_amdgcn_fdot2)
#define HAVE_FDOT2 1
#endif
#endif

__device__ __forceinline__ float fdot2(v2h a, v2h b, float c) {
#ifdef HAVE_FDOT2
  return __builtin_amdgcn_fdot2(a, b, c, false);
#else
  return (float)a[0] * (float)b[0] + ((float)a[1] * (float)b[1] + c);
#endif
}

// ---------------- K0x: pack x into MFMA-fragment layout + x_h + weight cvt ----
// Split by ci-32-group s: grid (7 hw-tiles, 3 s, NB) = 1344 blocks.
__global__ __launch_bounds__(256) void k0x_pack(const float* __restrict__ x,
                                                const float* __restrict__ w_exp,
                                                const float* __restrict__ w_proj,
                                                _Float16* __restrict__ x_f,
                                                _Float16* __restrict__ x_h,
                                                _Float16* __restrict__ w_exp_h,
                                                _Float16* __restrict__ w_proj_h) {
  __shared__ _Float16 xl[112][40];   // [hw_local][ci32], pad 32->40
  const int tid = threadIdx.x;
  const int s = blockIdx.y;
  const int n = blockIdx.z;
  const int hw0 = blockIdx.x * 112;

  if (n == 0 && s == 0) {  // weight conversion folded in (7 blocks)
    for (int i = blockIdx.x * 256 + tid; i < CE * CI; i += 7 * 256) {
      w_exp_h[i]  = (_Float16)w_exp[i];
      w_proj_h[i] = (_Float16)w_proj[i];
    }
  }

  for (int idx = tid; idx < 32 * 28; idx += 256) {
    int c_l = idx / 28, seg = idx % 28;
    int c = s * 32 + c_l;
    const float4 v = *(const float4*)&x[(n * CI + c) * HW + hw0 + seg * 4];
    v4h xh;
    xh[0] = (_Float16)(v.x - 128.0f);
    xh[1] = (_Float16)(v.y - 128.0f);
    xh[2] = (_Float16)(v.z - 128.0f);
    xh[3] = (_Float16)(v.w - 128.0f);
    int row = seg * 4;
    xl[row + 0][c_l] = xh[0];
    xl[row + 1][c_l] = xh[1];
    xl[row + 2][c_l] = xh[2];
    xl[row + 3][c_l] = xh[3];
    *(v4h*)&x_h[(n * CI + c) * HW + hw0 + seg * 4] = xh;   // k4 residual input
  }
  __syncthreads();

  for (int idx = tid; idx < 448; idx += 256) {   // 7 t_l * 64 lanes
    int t_l = idx / 64, ln = idx % 64;
    int hw_l = t_l * 16 + (ln & 15), ci = (ln >> 4) * 8;
    v8h o = *(const v8h*)&xl[hw_l][ci];          // aligned b128
    size_t t = (size_t)(blockIdx.x * 7 + t_l);
    *(v8h*)&x_f[(((size_t)n * 49 + t) * 3 + s) * 512 + ln * 8] = o;
  }
}

// ---------------- K12: FUSED expand 1x1 (MFMA) + depthwise 5x5 ---------------
// ROUND-11 EXACT (49.2 us): 512 thr / 8 waves, l<28 conv guard, shuffle pool
// reduce. Three later variants (all-fdot2 r10, 448-thr r12) both regressed —
// this is the measured local optimum for the fused kernel.
__global__ __launch_bounds__(512, 8) void k12_fused(const _Float16* __restrict__ x_f,
                                                    const _Float16* __restrict__ w_exp_h,
                                                    const float* __restrict__ b_exp,
                                                    const float* __restrict__ w_dw,
                                                    const float* __restrict__ b_dw,
                                                    _Float16* __restrict__ d_t,
                                                    float* __restrict__ d_sums2) {
  __shared__ _Float16 e_lds[16][18][42];   // 24192 B; row stride 21 dw (odd)
  __shared__ _Float16 d_tile[16][392];     // 12544 B
  __shared__ _Float16 w_pairs[16][5][8];   // 1280 B: [c][dy][w0..w3, w1..w4]
  const int tid = threadIdx.x;
  const int n = blockIdx.z;
  const int h = blockIdx.y;                // image half: rows 14h..14h+13
  const int c0 = blockIdx.x * 16;

  {
    unsigned long long* z = (unsigned long long*)&e_lds[0][0][0];
    for (int idx = tid; idx < 16 * 18 * 42 * 2 / 8; idx += 512) z[idx] = 0ull;
  }
  for (int idx = tid; idx < 640; idx += 512) {
    int c = idx / 40, r = idx % 40, dy = r / 8, k = r % 8;
    int tap = (k < 4) ? k : (k - 3);
    w_pairs[c][dy][k] = (_Float16)w_dw[(c0 + c) * 25 + dy * 5 + tap];
  }
  __syncthreads();

  const int wv = tid >> 6, lane = tid & 63;
  const int l15 = lane & 15, q = lane >> 4;

  // ---- phase 1: expand GEMM; lane owns pixels t*16+q*4..+3 of channel c0+l15 --
  {
    const _Float16* wrow = &w_exp_h[(c0 + l15) * CI + q * 8];
    v8h b0 = *(const v8h*)(wrow);          // B-frag: n=channel, k=ci
    v8h b1 = *(const v8h*)(wrow + 32);
    v8h b2 = *(const v8h*)(wrow + 64);
    const float bia = b_exp[c0 + l15];

    const int ir0 = 14 * h - 2;            // input row stored at LDS row 0
    const _Float16* xb = x_f + (size_t)n * (49 * 3 * 512) + lane * 8;
    for (int t_l = wv; t_l < 28; t_l += 8) {
      int t = 21 * h + t_l;
      const _Float16* xt = xb + (size_t)t * (3 * 512);
      v8h a0 = *(const v8h*)(xt);          // A-frag: m=pixel, k=ci
      v8h a1 = *(const v8h*)(xt + 512);
      v8h a2 = *(const v8h*)(xt + 1024);
      v4f acc = (v4f){0.f, 0.f, 0.f, 0.f};
      acc = __builtin_amdgcn_mfma_f32_16x16x32_f16(a0, b0, acc, 0, 0, 0);
      acc = __builtin_amdgcn_mfma_f32_16x16x32_f16(a1, b1, acc, 0, 0, 0);
      acc = __builtin_amdgcn_mfma_f32_16x16x32_f16(a2, b2, acc, 0, 0, 0);
      int p = t * 16 + q * 4;              // 4 consecutive pixels, same row
      int y = p / 28, xx = p - y * 28;     // xx % 4 == 0
      int r_l = y - ir0;
      v4h ev;
#pragma unroll
      for (int r = 0; r < 4; ++r) {
        float deq = (acc[r] + bia) * 5.0e-4f;               // S_IN * W_SCALE
        float cl  = fminf(fmaxf(deq + 3.0f, 0.0f), 6.0f);
        float evf = fminf(fmaxf(deq * cl * (25.0f / 6.0f), -128.0f), 127.0f); // e-128
        ev[r] = (_Float16)evf;
      }
      *(v4h*)&e_lds[l15][r_l][8 + xx] = ev;   // 8B-aligned b64
    }
  }
  __syncthreads();

  // ---- phase 2: depthwise 5x5 (round-9 form); lane = (ry = l>>1, xh = l&1) ----
  const int c = tid >> 5, l = tid & 31;
  v2h W01[5], W23[5], W12[5], W34[5];
  float W0s[5], W4s[5];
#pragma unroll
  for (int dy = 0; dy < 5; ++dy) {
    W01[dy] = *(const v2h*)&w_pairs[c][dy][0];
    W23[dy] = *(const v2h*)&w_pairs[c][dy][2];
    W12[dy] = *(const v2h*)&w_pairs[c][dy][4];
    W34[dy] = *(const v2h*)&w_pairs[c][dy][6];
    W0s[dy] = (float)W01[dy][0];
    W4s[dy] = (float)W34[dy][1];
  }
  const float bc = b_dw[c0 + c];

  float csum = 0.0f;
  if (l < 28) {
    const int ry = l >> 1;       // local output row 0..13
    const int bx = (l & 1) * 14; // x-half base
    v2h P0[5], P1[5], P2[5], P3[5];
#pragma unroll
    for (int dy = 0; dy < 5; ++dy) {
      const _Float16* row = &e_lds[c][ry + dy][bx];
      P0[dy] = *(const v2h*)(row + 6);
      P1[dy] = *(const v2h*)(row + 8);
      P2[dy] = *(const v2h*)(row + 10);
      P3[dy] = *(const v2h*)(row + 12);
    }
#pragma unroll
    for (int xi = 0; xi < 3; ++xi) {      // x0 = bx, bx+4, bx+8
      const int x0 = bx + xi * 4;
      float o0 = bc, o1 = bc, o2 = bc, o3 = bc;
#pragma unroll
      for (int dy = 0; dy < 5; ++dy) {
        o0 = fdot2(P0[dy], W01[dy], o0);
        o0 = fdot2(P1[dy], W23[dy], o0);
        o0 += (float)P2[dy][0] * W4s[dy];
        o1 += (float)P0[dy][1] * W0s[dy];
        o1 = fdot2(P1[dy], W12[dy], o1);
        o1 = fdot2(P2[dy], W34[dy], o1);
        o2 = fdot2(P1[dy], W01[dy], o2);
        o2 = fdot2(P2[dy], W23[dy], o2);
        o2 += (float)P3[dy][0] * W4s[dy];
        o3 += (float)P1[dy][1] * W0s[dy];
        o3 = fdot2(P2[dy], W12[dy], o3);
        o3 = fdot2(P3[dy], W34[dy], o3);
      }
      float oo[4] = {o0, o1, o2, o3};
      v2h dva, dvb;
#pragma unroll
      for (int i = 0; i < 4; ++i) {
        float deq = oo[i] * 4.0e-4f;            // S1 * W_SCALE
        float cl  = fminf(fmaxf(deq + 3.0f, 0.0f), 6.0f);
        float dvv = fminf(fmaxf(deq * cl * (25.0f / 6.0f), -128.0f), 127.0f); // d-128
        if (i < 2) dva[i] = (_Float16)dvv; else dvb[i - 2] = (_Float16)dvv;
        csum += dvv;
      }
      *(v2h*)&d_tile[c][ry * 28 + x0]     = dva;
      *(v2h*)&d_tile[c][ry * 28 + x0 + 2] = dvb;
#pragma unroll
      for (int dy = 0; dy < 5; ++dy) {        // slide; reads stay in-row (zero tail)
        const _Float16* row = &e_lds[c][ry + dy][bx];
        P0[dy] = P2[dy];
        P1[dy] = P3[dy];
        P2[dy] = *(const v2h*)(row + x0 - bx + 14);
        P3[dy] = *(const v2h*)(row + x0 - bx + 16);
      }
    }
    {  // tail: x0 = bx+12, outputs o0,o1 only
      float o0 = bc, o1 = bc;
#pragma unroll
      for (int dy = 0; dy < 5; ++dy) {
        o0 = fdot2(P0[dy], W01[dy], o0);
        o0 = fdot2(P1[dy], W23[dy], o0);
        o0 += (float)P2[dy][0] * W4s[dy];
        o1 += (float)P0[dy][1] * W0s[dy];
        o1 = fdot2(P1[dy], W12[dy], o1);
        o1 = fdot2(P2[dy], W34[dy], o1);
      }
      v2h dv;
      float oo[2] = {o0, o1};
#pragma unroll
      for (int i = 0; i < 2; ++i) {
        float deq = oo[i] * 4.0e-4f;
        float cl  = fminf(fmaxf(deq + 3.0f, 0.0f), 6.0f);
        float dvv = fminf(fmaxf(deq * cl * (25.0f / 6.0f), -128.0f), 127.0f);
        dv[i] = (_Float16)dvv;
        csum += dvv;
      }
      *(v2h*)&d_tile[c][ry * 28 + bx + 12] = dv;
    }
  }
#pragma unroll
  for (int m = 16; m >= 1; m >>= 1) csum += __shfl_xor(csum, m);
  if (l == 0) d_sums2[((size_t)h * NB + n) * CE + c0 + c] = csum;

  __syncthreads();
  // ---- phase 3: k-packed writeout d_t[n][cg][hw][8], hw in [392h, 392h+392) ----
  const size_t obase = ((size_t)n * 72 + (c0 >> 3)) * 784 + 392 * h;
  if (tid < 392) {
    int hw_l = tid;
    v8h o0, o1;
#pragma unroll
    for (int j = 0; j < 8; ++j) { o0[j] = d_tile[j][hw_l]; o1[j] = d_tile[8 + j][hw_l]; }
    *(v8h*)&d_t[(obase + hw_l) * 8] = o0;
    *(v8h*)&d_t[(obase + 784 + hw_l) * 8] = o1;
  }
}

// ---------------- K3a: SE fc1 — one wave per (n, o); sums 2 pool partials -----
__global__ __launch_bounds__(256) void k3a_fc1(const float* __restrict__ d_sums2,
                                               const float* __restrict__ w_se1,
                                               const float* __restrict__ b_se1,
                                               float* __restrict__ g1) {
  const int tid = threadIdx.x;
  const int wv = tid >> 6, lane = tid & 63;
  const int n = blockIdx.y;
  const int o = blockIdx.x * 4 + wv;       // 144 outputs
  const float* wrow = &w_se1[o * CE];
  const float* s0 = &d_sums2[(size_t)n * CE];
  const float* s1 = &d_sums2[((size_t)NB + n) * CE];
  float p = 0.f;
#pragma unroll
  for (int s = 0; s < 9; ++s) {
    int cc = lane + s * 64;
    p += wrow[cc] * (s0[cc] + s1[cc]);
  }
#pragma unroll
  for (int m = 32; m >= 1; m >>= 1) p += __shfl_xor(p, m);
  if (lane == 0) {
    float deq = (p * (1.0f / 784.0f) + b_se1[o]) * 4.0e-4f;  // S2 * W_SCALE
    g1[n * SEC + o] = fminf(fmaxf(deq * 33.3333333f + 128.0f, 0.0f), 255.0f) - 128.0f;
  }
}

// ---------------- K3b: SE fc2 + hardsigmoid -> f16 gate table -----------------
__global__ __launch_bounds__(256) void k3b_fc2(const float* __restrict__ g1,
                                               const float* __restrict__ w_se2,
                                               const float* __restrict__ b_se2,
                                               _Float16* __restrict__ g2h) {
  const int tid = threadIdx.x;
  const int wv = tid >> 6, lane = tid & 63;
  const int n = blockIdx.y;
  const int o = blockIdx.x * 4 + wv;       // 576 outputs
  const float* wrow = &w_se2[o * SEC];
  const float* grow = &g1[n * SEC];
  float p = wrow[lane] * grow[lane] + wrow[lane + 64] * grow[lane + 64];
  if (lane < 16) p += wrow[lane + 128] * grow[lane + 128];
#pragma unroll
  for (int m = 32; m >= 1; m >>= 1) p += __shfl_xor(p, m);
  if (lane == 0) {
    float deq = (p + b_se2[o]) * 3.0e-4f;  // S_SE1 * W_SCALE
    g2h[n * CE + o] =
        (_Float16)(fminf(fmaxf(deq + 3.0f, 0.0f), 6.0f) * (1.0f / 6.0f)); // hardsigmoid
  }
}

// ---------------- K4: gated project 1x1 + residual add -> out fp32 -----------
// Software-pipelined ks-loop: while MFMAing iteration ks, the A/G + 7 B loads
// of ks+1 are already in flight (r4 lesson: no cross-iteration ILP = latency-
// bound; the 18 serial iterations were the suspected ~40us). No LDS/barriers.
__global__ __launch_bounds__(192) void k4_proj(const _Float16* __restrict__ d_t,
                                               const _Float16* __restrict__ g2h,
                                               const _Float16* __restrict__ w_proj_h,
                                               const float* __restrict__ b_proj,
                                               const _Float16* __restrict__ x_h,
                                               float* __restrict__ out) {
  const int tid = threadIdx.x;
  const int n = blockIdx.z;
  const int co0 = blockIdx.y * 48;
  const int hw0 = blockIdx.x * 112;
  const int wv = tid >> 6, lane = tid & 63;
  const int l15 = lane & 15, q = lane >> 4;

  v4f acc[7];
#pragma unroll
  for (int t = 0; t < 7; ++t) acc[t] = (v4f){0.f, 0.f, 0.f, 0.f};

  const _Float16* dbase = d_t + (((size_t)n * 72 + q) * 784 + hw0 + l15) * 8;
  const _Float16* abase = &w_proj_h[(co0 + wv * 16 + l15) * CE + q * 8];
  const _Float16* gbase = &g2h[(size_t)n * CE + q * 8];
  const size_t KS = (size_t)4 * 784 * 8;   // d_t stride per ks

  // prologue: ks = 0 operands
  v8h a = *(const v8h*)(abase);
  v8h g = *(const v8h*)(gbase);
  v8h b[7];
#pragma unroll
  for (int t = 0; t < 7; ++t) b[t] = *(const v8h*)(dbase + t * 128);

  for (int ks = 0; ks < 17; ++ks) {
    // issue next-iteration loads first (independent of current MFMAs)
    v8h a2 = *(const v8h*)(abase + (ks + 1) * 32);
    v8h g2 = *(const v8h*)(gbase + (ks + 1) * 32);
    v8h b2[7];
    const _Float16* dk2 = dbase + (size_t)(ks + 1) * KS;
#pragma unroll
    for (int t = 0; t < 7; ++t) b2[t] = *(const v8h*)(dk2 + t * 128);

    v8h ag = a * g;   // 4x v_pk_mul_f16
#pragma unroll
    for (int t = 0; t < 7; ++t)
      acc[t] = __builtin_amdgcn_mfma_f32_16x16x32_f16(ag, b[t], acc[t], 0, 0, 0);

    a = a2; g = g2;
#pragma unroll
    for (int t = 0; t < 7; ++t) b[t] = b2[t];
  }
  {  // epilogue: ks = 17
    v8h ag = a * g;
#pragma unroll
    for (int t = 0; t < 7; ++t)
      acc[t] = __builtin_amdgcn_mfma_f32_16x16x32_f16(ag, b[t], acc[t], 0, 0, 0);
  }

  float bia[4];
#pragma unroll
  for (int r = 0; r < 4; ++r) bia[r] = b_proj[co0 + wv * 16 + q * 4 + r];

#pragma unroll
  for (int t = 0; t < 7; ++t) {
#pragma unroll
    for (int r = 0; r < 4; ++r) {
      int co = co0 + wv * 16 + q * 4 + r;
      int hw = hw0 + t * 16 + l15;
      float p = fminf(fmaxf((acc[t][r] + bia[r]) * 4.0e-4f * 20.0f + 128.0f, 0.0f), 255.0f);
      float xv = (float)x_h[(n * CO + co) * HW + hw];   // x - 128, f16-exact
      float o = xv * 0.8333333333f + (p - 128.0f) * 0.8333333333f + 128.0f;
      out[(n * CO + co) * HW + hw] = fminf(fmaxf(o, 0.0f), 255.0f);
    }
  }
}

extern "C" void kernel_launch(void* const* d_in, const int* in_sizes, int n_in,
                              void* d_out, int out_size, void* d_ws, size_t ws_size,
                              hipStream_t stream) {
  const float* x      = (const float*)d_in[0];
  const float* w_exp  = (const float*)d_in[1];
  const float* b_exp  = (const float*)d_in[2];
  const float* w_dw   = (const float*)d_in[3];
  const float* b_dw   = (const float*)d_in[4];
  const float* w_se1  = (const float*)d_in[5];
  const float* b_se1  = (const float*)d_in[6];
  const float* w_se2  = (const float*)d_in[7];
  const float* b_se2  = (const float*)d_in[8];
  const float* w_proj = (const float*)d_in[9];
  const float* b_proj = (const float*)d_in[10];
  float* out = (float*)d_out;

  char* ws = (char*)d_ws;
  const size_t SZ_W  = (size_t)CE * CI * 2;            // 110592 B
  const size_t SZ_XF = (size_t)NB * 49 * 3 * 512 * 2;  // 9633792 B
  const size_t SZ_XH = (size_t)NB * CI * HW * 2;       // 9633792 B
  const size_t SZ_D  = (size_t)NB * CE * HW * 2;       // 57802752 B
  const size_t SZ_S2 = (size_t)2 * NB * CE * 4;        // 294912 B
  const size_t SZ_S  = (size_t)NB * CE * 4;            // 147456 B
  _Float16* w_exp_h  = (_Float16*)(ws);
  _Float16* w_proj_h = (_Float16*)(ws + SZ_W);
  _Float16* x_f      = (_Float16*)(ws + 2 * SZ_W);
  _Float16* x_h      = (_Float16*)(ws + 2 * SZ_W + SZ_XF);
  _Float16* d_t      = (_Float16*)(ws + 2 * SZ_W + SZ_XF + SZ_XH);  // [n][72][784][8]
  float*    d_sums2  = (float*)   (ws + 2 * SZ_W + SZ_XF + SZ_XH + SZ_D);
  float*    g1       = (float*)   (ws + 2 * SZ_W + SZ_XF + SZ_XH + SZ_D + SZ_S2);
  _Float16* g2h      = (_Float16*)(ws + 2 * SZ_W + SZ_XF + SZ_XH + SZ_D + SZ_S2 + SZ_S);
  // total ws use: ~78 MB

  k0x_pack<<<dim3(7, 3, NB), 256, 0, stream>>>(x, w_exp, w_proj, x_f, x_h, w_exp_h, w_proj_h);
  k12_fused<<<dim3(36, 2, NB), 512, 0, stream>>>(x_f, w_exp_h, b_exp, w_dw, b_dw, d_t, d_sums2);
  k3a_fc1<<<dim3(36, NB), 256, 0, stream>>>(d_sums2, w_se1, b_se1, g1);
  k3b_fc2<<<dim3(144, NB), 256, 0, stream>>>(g1, w_se2, b_se2, g2h);
  k4_proj<<<dim3(7, 2, NB), 192, 0, stream>>>(d_t, g2h, w_proj_h, b_proj, x_h, out);
}